// Round 1
// baseline (2703.806 us; speedup 1.0000x reference)
//
#include <hip/hip_runtime.h>
#include <cstdint>
#include <cstddef>

#define HD    1024
#define SLOTS 272
#define MEMS  256
#define BATCH 8
#define TT    4096
#define RR    (BATCH*TT)
#define RANKC 10

#define GAMMA 0.92f
#define BETA  0.08f
#define PTS   0.4f

// ---------------------------------------------------------------------------
// prep: per-slot constants (sigmoid gates, rotation cos/sin, normalized tape0),
// eta = softplus(eta_raw), and wave-uniform flags for the rank-term fast path.
// consts layout (floats): [0]=wr_gate[256] [256]=bg[256] [512]=cos[256]
// [768]=sin[256] [1024]=z0re[256] [1280]=z0im[256] [1536]=eta
// ---------------------------------------------------------------------------
__global__ void prep_kernel(const float* __restrict__ t0re, const float* __restrict__ t0im,
                            const float* __restrict__ eta_raw,
                            const float* __restrict__ trot, const float* __restrict__ w_r,
                            const float* __restrict__ bgate,
                            const float* __restrict__ eps_scale, const float* __restrict__ pred_scale,
                            float* __restrict__ consts, int* __restrict__ flags)
{
    __shared__ float red[MEMS];
    const int s = threadIdx.x;  // 256 threads
    const float tr = t0re[s], ti = t0im[s];
    red[s] = tr * tr + ti * ti;
    __syncthreads();
    for (int off = 128; off > 0; off >>= 1) {
        if (s < off) red[s] += red[s + off];
        __syncthreads();
    }
    const float nrm = sqrtf(fmaxf(red[0], 1e-16f));
    consts[0 * MEMS + s] = 1.0f / (1.0f + expf(-w_r[s]));
    consts[1 * MEMS + s] = 1.0f / (1.0f + expf(-bgate[s]));
    consts[2 * MEMS + s] = cosf(trot[s]);
    consts[3 * MEMS + s] = sinf(trot[s]);
    consts[4 * MEMS + s] = tr / nrm;
    consts[5 * MEMS + s] = ti / nrm;
    if (s == 0) {
        consts[6 * MEMS] = log1pf(expf(eta_raw[0]));
        int f1 = 0, f2 = 0;
        for (int k = 0; k < RANKC; ++k) {
            if (eps_scale[k]  != 0.0f) f1 = 1;
            if (pred_scale[k] != 0.0f) f2 = 1;
        }
        flags[0] = f1;
        flags[1] = f2;
    }
}

// ---------------------------------------------------------------------------
// proj: M(R x 256) = X(R x 1024) * Q,  Q[k][n] = basis[k*272 + n]
// 64x64 tile, BK=32, 256 threads, 4x4 microtile per thread. fp32.
// ---------------------------------------------------------------------------
__global__ __launch_bounds__(256) void proj_kernel(const float* __restrict__ x,
                                                   const float* __restrict__ basis,
                                                   float* __restrict__ M)
{
    __shared__ float As[32][68];  // [k][m], padded
    __shared__ float Bs[32][68];  // [k][n], padded
    const int tid  = threadIdx.x;
    const int row0 = blockIdx.x * 64;
    const int col0 = blockIdx.y * 64;
    const int mt = tid >> 4, nt = tid & 15;
    float acc[4][4] = {};
    for (int k0 = 0; k0 < HD; k0 += 32) {
        {
            int q = tid, m = q >> 3, kq = q & 7;
            float4 a = *(const float4*)&x[(size_t)(row0 + m) * HD + k0 + kq * 4];
            As[kq * 4 + 0][m] = a.x; As[kq * 4 + 1][m] = a.y;
            As[kq * 4 + 2][m] = a.z; As[kq * 4 + 3][m] = a.w;
            q = tid + 256; m = q >> 3; kq = q & 7;
            float4 b = *(const float4*)&x[(size_t)(row0 + m) * HD + k0 + kq * 4];
            As[kq * 4 + 0][m] = b.x; As[kq * 4 + 1][m] = b.y;
            As[kq * 4 + 2][m] = b.z; As[kq * 4 + 3][m] = b.w;
            q = tid; int k = q >> 4; int nq = q & 15;
            float4 c = *(const float4*)&basis[(size_t)(k0 + k) * SLOTS + col0 + nq * 4];
            *(float4*)&Bs[k][nq * 4] = c;
            q = tid + 256; k = q >> 4; nq = q & 15;
            float4 d = *(const float4*)&basis[(size_t)(k0 + k) * SLOTS + col0 + nq * 4];
            *(float4*)&Bs[k][nq * 4] = d;
        }
        __syncthreads();
#pragma unroll
        for (int kk = 0; kk < 32; ++kk) {
            float4 a = *(const float4*)&As[kk][mt * 4];
            float4 b = *(const float4*)&Bs[kk][nt * 4];
            float av[4] = {a.x, a.y, a.z, a.w};
            float bv[4] = {b.x, b.y, b.z, b.w};
#pragma unroll
            for (int i = 0; i < 4; ++i)
#pragma unroll
                for (int j = 0; j < 4; ++j) acc[i][j] += av[i] * bv[j];
        }
        __syncthreads();
    }
#pragma unroll
    for (int i = 0; i < 4; ++i) {
        float4 o = {acc[i][0], acc[i][1], acc[i][2], acc[i][3]};
        *(float4*)&M[(size_t)(row0 + mt * 4 + i) * MEMS + col0 + nt * 4] = o;
    }
}

// ---------------------------------------------------------------------------
// topk: per (b,t) row of M, find the 8th-largest |m| (counting duplicates).
// One wave per row; iterative extract-max with low-index tiebreak.
// ---------------------------------------------------------------------------
__global__ __launch_bounds__(64) void topk_kernel(const float* __restrict__ M,
                                                  float* __restrict__ kth)
{
    const int r    = blockIdx.x;
    const int lane = threadIdx.x;
    const float4 v = *(const float4*)&M[(size_t)r * MEMS + lane * 4];
    float vals[4] = {fabsf(v.x), fabsf(v.y), fabsf(v.z), fabsf(v.w)};
    float kv = 0.0f;
#pragma unroll
    for (int it = 0; it < 8; ++it) {
        float lm = vals[0]; int li = 0;
#pragma unroll
        for (int j = 1; j < 4; ++j)
            if (vals[j] > lm) { lm = vals[j]; li = j; }
        float bm = lm; int bi = lane * 4 + li;
#pragma unroll
        for (int off = 1; off < 64; off <<= 1) {
            float om = __shfl_xor(bm, off);
            int   oi = __shfl_xor(bi, off);
            if (om > bm || (om == bm && oi < bi)) { bm = om; bi = oi; }
        }
        kv = bm;
        if ((bi >> 2) == lane) vals[bi & 3] = -1.0f;
    }
    if (lane == 0) kth[r] = kv;
}

// ---------------------------------------------------------------------------
// scan: the sequential recurrence. One wave per batch, 4 slots per lane,
// all state in registers, wave-shuffle norm reduction, depth-4 prefetch.
// Writes Wout[b,t,s] = bg[s] * new_re[b,t,s].
// ---------------------------------------------------------------------------
__device__ __forceinline__ float wave_allreduce_sum(float v)
{
#pragma unroll
    for (int off = 1; off < 64; off <<= 1) v += __shfl_xor(v, off);
    return v;
}

__global__ __launch_bounds__(64) void scan_kernel(const float* __restrict__ M,
                                                  const float* __restrict__ kth,
                                                  const float* __restrict__ consts,
                                                  const int* __restrict__ flags,
                                                  const float* __restrict__ eps_fac,
                                                  const float* __restrict__ eps_scale,
                                                  const float* __restrict__ eps_diag,
                                                  const float* __restrict__ pred_fac,
                                                  const float* __restrict__ pred_scale,
                                                  const float* __restrict__ pred_diag,
                                                  float* __restrict__ Wout)
{
    const int b    = blockIdx.x;
    const int lane = threadIdx.x;
    const int s0   = lane * 4;
    float wr4[4], bg4[4], rc4[4], rs4[4], ed4[4], pd4[4], zr[4], zi[4], pr[4], pi[4];
#pragma unroll
    for (int i = 0; i < 4; ++i) {
        wr4[i] = consts[0 * MEMS + s0 + i];
        bg4[i] = consts[1 * MEMS + s0 + i];
        rc4[i] = consts[2 * MEMS + s0 + i];
        rs4[i] = consts[3 * MEMS + s0 + i];
        zr[i]  = consts[4 * MEMS + s0 + i];
        zi[i]  = consts[5 * MEMS + s0 + i];
        pr[i] = zr[i]; pi[i] = zi[i];
        ed4[i] = eps_diag[s0 + i];
        pd4[i] = pred_diag[s0 + i];
    }
    const float eta   = consts[6 * MEMS];
    const int es_any  = flags[0];
    const int ps_any  = flags[1];
    const size_t base = (size_t)b * TT * MEMS + s0;

    // depth-4 prefetch ring
    float4 mbuf[4];
    float  kb4[4];
#pragma unroll
    for (int j = 0; j < 4; ++j) {
        mbuf[j] = *(const float4*)&M[base + (size_t)j * MEMS];
        kb4[j]  = kth[b * TT + j];
    }

    for (int t0 = 0; t0 < TT; t0 += 4) {
#pragma unroll
        for (int j = 0; j < 4; ++j) {
            const int t = t0 + j;
            const float4 mcur = mbuf[j];
            const float  kcur = kb4[j];
            if (t + 4 < TT) {
                mbuf[j] = *(const float4*)&M[base + (size_t)(t + 4) * MEMS];
                kb4[j]  = kth[b * TT + t + 4];
            }
            float rr[4], ri[4], nr[4], ni[4];
#pragma unroll
            for (int i = 0; i < 4; ++i) {
                rr[i] = zr[i] * rc4[i] - zi[i] * rs4[i];
                ri[i] = zr[i] * rs4[i] + zi[i] * rc4[i];
            }
            const float mv[4] = {mcur.x, mcur.y, mcur.z, mcur.w};
#pragma unroll
            for (int i = 0; i < 4; ++i) {
                const float inj = (fabsf(mv[i]) >= kcur) ? mv[i] : 0.0f;
                nr[i] = GAMMA * rr[i] + wr4[i] * pr[i] + eta * ed4[i] * rr[i]
                        - PTS * pd4[i] * ri[i] + BETA * inj;
                ni[i] = GAMMA * ri[i] + wr4[i] * pi[i] + eta * ed4[i] * ri[i]
                        + PTS * pd4[i] * rr[i];
            }
            if (es_any) {  // rank-10 Hermitian coupling drive (general path)
#pragma unroll
                for (int k = 0; k < RANKC; ++k) {
                    float u[4], prj = 0.0f, pij = 0.0f;
#pragma unroll
                    for (int i = 0; i < 4; ++i) {
                        u[i] = eps_fac[(size_t)(s0 + i) * RANKC + k];
                        prj += u[i] * rr[i];
                        pij += u[i] * ri[i];
                    }
                    prj = wave_allreduce_sum(prj);
                    pij = wave_allreduce_sum(pij);
                    const float sc = eta * eps_scale[k];
#pragma unroll
                    for (int i = 0; i < 4; ++i) {
                        nr[i] += sc * u[i] * prj;
                        ni[i] += sc * u[i] * pij;
                    }
                }
            }
            if (ps_any) {  // rank-10 prediction torque (general path)
#pragma unroll
                for (int k = 0; k < RANKC; ++k) {
                    float u[4], qrj = 0.0f, qij = 0.0f;
#pragma unroll
                    for (int i = 0; i < 4; ++i) {
                        u[i] = pred_fac[(size_t)(s0 + i) * RANKC + k];
                        qrj += u[i] * rr[i];
                        qij += u[i] * ri[i];
                    }
                    qrj = wave_allreduce_sum(qrj);
                    qij = wave_allreduce_sum(qij);
                    const float sc = PTS * pred_scale[k];
#pragma unroll
                    for (int i = 0; i < 4; ++i) {
                        nr[i] -= sc * u[i] * qij;  // PTS * i * pred : re -= sc*pred_im
                        ni[i] += sc * u[i] * qrj;  //                  im += sc*pred_re
                    }
                }
            }
            float ss = 0.0f;
#pragma unroll
            for (int i = 0; i < 4; ++i) ss += nr[i] * nr[i] + ni[i] * ni[i];
            ss = wave_allreduce_sum(ss);
            const float inv = 1.0f / sqrtf(fmaxf(ss, 1e-16f));
            float wv[4];
#pragma unroll
            for (int i = 0; i < 4; ++i) {
                const float znr = nr[i] * inv, zni = ni[i] * inv;
                pr[i] = zr[i]; pi[i] = zi[i];
                zr[i] = znr;   zi[i] = zni;
                wv[i] = bg4[i] * znr;
            }
            float4 wq = {wv[0], wv[1], wv[2], wv[3]};
            *(float4*)&Wout[base + (size_t)t * MEMS] = wq;
        }
    }
}

// ---------------------------------------------------------------------------
// outp: Y(R x 1024) = X + alpha * W(R x 256) * basisT, basisT[k][n]=basis[n*272+k]
// ---------------------------------------------------------------------------
__global__ __launch_bounds__(256) void outp_kernel(const float* __restrict__ W,
                                                   const float* __restrict__ basis,
                                                   const float* __restrict__ x,
                                                   const float* __restrict__ alpha_p,
                                                   float* __restrict__ y)
{
    __shared__ float As[32][68];  // [k][m]
    __shared__ float Bs[32][68];  // [k][n]
    const int tid  = threadIdx.x;
    const int row0 = blockIdx.x * 64;
    const int col0 = blockIdx.y * 64;  // h
    const int mt = tid >> 4, nt = tid & 15;
    float acc[4][4] = {};
    for (int k0 = 0; k0 < MEMS; k0 += 32) {
        {
            int q = tid, m = q >> 3, kq = q & 7;
            float4 a = *(const float4*)&W[(size_t)(row0 + m) * MEMS + k0 + kq * 4];
            As[kq * 4 + 0][m] = a.x; As[kq * 4 + 1][m] = a.y;
            As[kq * 4 + 2][m] = a.z; As[kq * 4 + 3][m] = a.w;
            q = tid + 256; m = q >> 3; kq = q & 7;
            float4 b = *(const float4*)&W[(size_t)(row0 + m) * MEMS + k0 + kq * 4];
            As[kq * 4 + 0][m] = b.x; As[kq * 4 + 1][m] = b.y;
            As[kq * 4 + 2][m] = b.z; As[kq * 4 + 3][m] = b.w;
            q = tid; int n = q >> 3; kq = q & 7;
            float4 c = *(const float4*)&basis[(size_t)(col0 + n) * SLOTS + k0 + kq * 4];
            Bs[kq * 4 + 0][n] = c.x; Bs[kq * 4 + 1][n] = c.y;
            Bs[kq * 4 + 2][n] = c.z; Bs[kq * 4 + 3][n] = c.w;
            q = tid + 256; n = q >> 3; kq = q & 7;
            float4 d = *(const float4*)&basis[(size_t)(col0 + n) * SLOTS + k0 + kq * 4];
            Bs[kq * 4 + 0][n] = d.x; Bs[kq * 4 + 1][n] = d.y;
            Bs[kq * 4 + 2][n] = d.z; Bs[kq * 4 + 3][n] = d.w;
        }
        __syncthreads();
#pragma unroll
        for (int kk = 0; kk < 32; ++kk) {
            float4 a = *(const float4*)&As[kk][mt * 4];
            float4 b = *(const float4*)&Bs[kk][nt * 4];
            float av[4] = {a.x, a.y, a.z, a.w};
            float bv[4] = {b.x, b.y, b.z, b.w};
#pragma unroll
            for (int i = 0; i < 4; ++i)
#pragma unroll
                for (int j = 0; j < 4; ++j) acc[i][j] += av[i] * bv[j];
        }
        __syncthreads();
    }
    const float alpha = alpha_p[0];
#pragma unroll
    for (int i = 0; i < 4; ++i) {
        const size_t ro = (size_t)(row0 + mt * 4 + i) * HD + col0 + nt * 4;
        float4 xv = *(const float4*)&x[ro];
        float4 o  = {xv.x + alpha * acc[i][0], xv.y + alpha * acc[i][1],
                     xv.z + alpha * acc[i][2], xv.w + alpha * acc[i][3]};
        *(float4*)&y[ro] = o;
    }
}

// ---------------------------------------------------------------------------
extern "C" void kernel_launch(void* const* d_in, const int* in_sizes, int n_in,
                              void* d_out, int out_size, void* d_ws, size_t ws_size,
                              hipStream_t stream)
{
    const float* x          = (const float*)d_in[0];
    const float* basis      = (const float*)d_in[1];
    const float* t0re       = (const float*)d_in[2];
    const float* t0im       = (const float*)d_in[3];
    const float* eta_raw    = (const float*)d_in[4];
    const float* alpha      = (const float*)d_in[5];
    const float* trot       = (const float*)d_in[6];
    const float* w_r        = (const float*)d_in[7];
    const float* bgate      = (const float*)d_in[8];
    const float* eps_fac    = (const float*)d_in[9];
    const float* eps_scale  = (const float*)d_in[10];
    const float* eps_diag   = (const float*)d_in[11];
    const float* pred_fac   = (const float*)d_in[12];
    const float* pred_scale = (const float*)d_in[13];
    const float* pred_diag  = (const float*)d_in[14];
    float* out = (float*)d_out;

    const size_t szM = (size_t)RR * MEMS * sizeof(float);  // 32 MB
    const size_t szW = szM;                                 // 32 MB
    const size_t szK = (size_t)RR * sizeof(float);          // 128 KB
    const size_t szC = 8192;                                // consts + flags

    char* ws = (char*)d_ws;
    float *Mbuf, *Wbuf, *kbuf, *cbuf;
    if (ws_size >= szM + szW + szK + szC) {
        Mbuf = (float*)(ws);
        Wbuf = (float*)(ws + szM);
        kbuf = (float*)(ws + szM + szW);
        cbuf = (float*)(ws + szM + szW + szK);
    } else {
        // fallback: stage M in d_out (consumed by topk+scan before outp rewrites it)
        Mbuf = (float*)d_out;
        Wbuf = (float*)(ws);
        kbuf = (float*)(ws + szW);
        cbuf = (float*)(ws + szW + szK);
    }
    int* fbuf = (int*)(cbuf + 6 * MEMS + 8);

    prep_kernel<<<1, 256, 0, stream>>>(t0re, t0im, eta_raw, trot, w_r, bgate,
                                       eps_scale, pred_scale, cbuf, fbuf);
    proj_kernel<<<dim3(RR / 64, MEMS / 64), 256, 0, stream>>>(x, basis, Mbuf);
    topk_kernel<<<RR, 64, 0, stream>>>(Mbuf, kbuf);
    scan_kernel<<<BATCH, 64, 0, stream>>>(Mbuf, kbuf, cbuf, fbuf,
                                          eps_fac, eps_scale, eps_diag,
                                          pred_fac, pred_scale, pred_diag, Wbuf);
    outp_kernel<<<dim3(RR / 64, HD / 64), 256, 0, stream>>>(Wbuf, basis, x, alpha, out);
}

// Round 2
// 1526.062 us; speedup vs baseline: 1.7718x; 1.7718x over previous
//
#include <hip/hip_runtime.h>
#include <cstdint>
#include <cstddef>

#define HD    1024
#define SLOTS 272
#define MEMS  256
#define BATCH 8
#define TT    4096
#define RR    (BATCH*TT)
#define RANKC 10

#define GAMMA 0.92f
#define BETA  0.08f
#define PTS   0.4f

// ---------------------------------------------------------------------------
// DPP wave64 sum-allreduce: 6 VALU-speed cross-lane adds + readlane broadcast.
// Levels: xor1 (quad_perm [1,0,3,2]), xor2 (quad_perm [2,3,0,1]),
// row_half_mirror (0x141), row_mirror (0x140) -> 16-lane row sums everywhere;
// row_bcast15 (0x142, rows 1&3), row_bcast31 (0x143, rows 2&3) -> lane 63 total.
// ---------------------------------------------------------------------------
#define DPP_ADD(v, ctrl, rmask)                                                   \
    v += __int_as_float(__builtin_amdgcn_update_dpp(                              \
        0, __float_as_int(v), (ctrl), (rmask), 0xf, true))

__device__ __forceinline__ float wave_sum_bcast(float v)
{
    DPP_ADD(v, 0xB1,  0xf);   // quad_perm [1,0,3,2]  : + lane^1
    DPP_ADD(v, 0x4E,  0xf);   // quad_perm [2,3,0,1]  : + lane^2
    DPP_ADD(v, 0x141, 0xf);   // row_half_mirror      : + other quad
    DPP_ADD(v, 0x140, 0xf);   // row_mirror           : + other 8-group
    DPP_ADD(v, 0x142, 0xa);   // row_bcast15 -> rows 1,3
    DPP_ADD(v, 0x143, 0xc);   // row_bcast31 -> rows 2,3 (lane 63 = total)
    return __int_as_float(__builtin_amdgcn_readlane(__float_as_int(v), 63));
}

// ---------------------------------------------------------------------------
// prep: per-slot constants.
// consts layout (floats): [0]=wr[256] [256]=bg[256] [512]=A[256] [768]=B[256]
// [1024]=z0re[256] [1280]=z0im[256] [1536]=cos[256] [1792]=sin[256] [2048]=eta
// A,B fold rotation + gamma + eta*eps_diag + PTS*pred_diag:
//   c1 = gamma + eta*ed, c2 = PTS*pd, A = c1*cos - c2*sin, B = c1*sin + c2*cos
// flags at int offset 2064: [0]=eps_scale any nonzero, [1]=pred_scale any.
// ---------------------------------------------------------------------------
__global__ void prep_kernel(const float* __restrict__ t0re, const float* __restrict__ t0im,
                            const float* __restrict__ eta_raw,
                            const float* __restrict__ trot, const float* __restrict__ w_r,
                            const float* __restrict__ bgate,
                            const float* __restrict__ eps_scale, const float* __restrict__ pred_scale,
                            const float* __restrict__ eps_diag, const float* __restrict__ pred_diag,
                            float* __restrict__ consts, int* __restrict__ flags)
{
    __shared__ float red[MEMS];
    const int s = threadIdx.x;  // 256 threads
    const float tr = t0re[s], ti = t0im[s];
    red[s] = tr * tr + ti * ti;
    __syncthreads();
    for (int off = 128; off > 0; off >>= 1) {
        if (s < off) red[s] += red[s + off];
        __syncthreads();
    }
    const float nrm = sqrtf(fmaxf(red[0], 1e-16f));
    const float eta = log1pf(expf(eta_raw[0]));
    const float rc = cosf(trot[s]), rs = sinf(trot[s]);
    const float c1 = GAMMA + eta * eps_diag[s];
    const float c2 = PTS * pred_diag[s];
    consts[0 * MEMS + s] = 1.0f / (1.0f + expf(-w_r[s]));
    consts[1 * MEMS + s] = 1.0f / (1.0f + expf(-bgate[s]));
    consts[2 * MEMS + s] = c1 * rc - c2 * rs;   // A
    consts[3 * MEMS + s] = c1 * rs + c2 * rc;   // B
    consts[4 * MEMS + s] = tr / nrm;
    consts[5 * MEMS + s] = ti / nrm;
    consts[6 * MEMS + s] = rc;
    consts[7 * MEMS + s] = rs;
    if (s == 0) {
        consts[8 * MEMS] = eta;
        int f1 = 0, f2 = 0;
        for (int k = 0; k < RANKC; ++k) {
            if (eps_scale[k]  != 0.0f) f1 = 1;
            if (pred_scale[k] != 0.0f) f2 = 1;
        }
        flags[0] = f1;
        flags[1] = f2;
    }
}

// ---------------------------------------------------------------------------
// proj: M(R x 256) = X(R x 1024) * Q,  Q[k][n] = basis[k*272 + n]
// ---------------------------------------------------------------------------
__global__ __launch_bounds__(256) void proj_kernel(const float* __restrict__ x,
                                                   const float* __restrict__ basis,
                                                   float* __restrict__ M)
{
    __shared__ float As[32][68];  // [k][m], padded
    __shared__ float Bs[32][68];  // [k][n], padded
    const int tid  = threadIdx.x;
    const int row0 = blockIdx.x * 64;
    const int col0 = blockIdx.y * 64;
    const int mt = tid >> 4, nt = tid & 15;
    float acc[4][4] = {};
    for (int k0 = 0; k0 < HD; k0 += 32) {
        {
            int q = tid, m = q >> 3, kq = q & 7;
            float4 a = *(const float4*)&x[(size_t)(row0 + m) * HD + k0 + kq * 4];
            As[kq * 4 + 0][m] = a.x; As[kq * 4 + 1][m] = a.y;
            As[kq * 4 + 2][m] = a.z; As[kq * 4 + 3][m] = a.w;
            q = tid + 256; m = q >> 3; kq = q & 7;
            float4 b = *(const float4*)&x[(size_t)(row0 + m) * HD + k0 + kq * 4];
            As[kq * 4 + 0][m] = b.x; As[kq * 4 + 1][m] = b.y;
            As[kq * 4 + 2][m] = b.z; As[kq * 4 + 3][m] = b.w;
            q = tid; int k = q >> 4; int nq = q & 15;
            float4 c = *(const float4*)&basis[(size_t)(k0 + k) * SLOTS + col0 + nq * 4];
            *(float4*)&Bs[k][nq * 4] = c;
            q = tid + 256; k = q >> 4; nq = q & 15;
            float4 d = *(const float4*)&basis[(size_t)(k0 + k) * SLOTS + col0 + nq * 4];
            *(float4*)&Bs[k][nq * 4] = d;
        }
        __syncthreads();
#pragma unroll
        for (int kk = 0; kk < 32; ++kk) {
            float4 a = *(const float4*)&As[kk][mt * 4];
            float4 b = *(const float4*)&Bs[kk][nt * 4];
            float av[4] = {a.x, a.y, a.z, a.w};
            float bv[4] = {b.x, b.y, b.z, b.w};
#pragma unroll
            for (int i = 0; i < 4; ++i)
#pragma unroll
                for (int j = 0; j < 4; ++j) acc[i][j] += av[i] * bv[j];
        }
        __syncthreads();
    }
#pragma unroll
    for (int i = 0; i < 4; ++i) {
        float4 o = {acc[i][0], acc[i][1], acc[i][2], acc[i][3]};
        *(float4*)&M[(size_t)(row0 + mt * 4 + i) * MEMS + col0 + nt * 4] = o;
    }
}

// ---------------------------------------------------------------------------
// topk: per (b,t) row of M, the 8th-largest |m| (dup-counting), one wave/row.
// ---------------------------------------------------------------------------
__global__ __launch_bounds__(64) void topk_kernel(const float* __restrict__ M,
                                                  float* __restrict__ kth)
{
    const int r    = blockIdx.x;
    const int lane = threadIdx.x;
    const float4 v = *(const float4*)&M[(size_t)r * MEMS + lane * 4];
    float vals[4] = {fabsf(v.x), fabsf(v.y), fabsf(v.z), fabsf(v.w)};
    float kv = 0.0f;
#pragma unroll
    for (int it = 0; it < 8; ++it) {
        float lm = vals[0]; int li = 0;
#pragma unroll
        for (int j = 1; j < 4; ++j)
            if (vals[j] > lm) { lm = vals[j]; li = j; }
        float bm = lm; int bi = lane * 4 + li;
#pragma unroll
        for (int off = 1; off < 64; off <<= 1) {
            float om = __shfl_xor(bm, off);
            int   oi = __shfl_xor(bi, off);
            if (om > bm || (om == bm && oi < bi)) { bm = om; bi = oi; }
        }
        kv = bm;
        if ((bi >> 2) == lane) vals[bi & 3] = -1.0f;
    }
    if (lane == 0) kth[r] = kv;
}

// ---------------------------------------------------------------------------
// scan: one wave per batch, 4 slots/lane, all state in registers.
// FAST PATH (rank scales all zero): deferred normalization — carry u (unnorm.)
// plus uniform scalars invc=1/||u_t||, invp=1/||u_{t-1}||:
//   u_{t+1} = invc*(A*u - B*conj-mix) + invp*wr*u_prev + beta*inj
// The DPP norm-reduction of u_{t+1} overlaps the per-lane linear work.
// GENERAL PATH: per-step renorm + rank-10 terms, DPP allreduce.
// ---------------------------------------------------------------------------
__global__ __launch_bounds__(64) void scan_kernel(const float* __restrict__ M,
                                                  const float* __restrict__ kth,
                                                  const float* __restrict__ consts,
                                                  const int* __restrict__ flags,
                                                  const float* __restrict__ eps_fac,
                                                  const float* __restrict__ eps_scale,
                                                  const float* __restrict__ eps_diag,
                                                  const float* __restrict__ pred_fac,
                                                  const float* __restrict__ pred_scale,
                                                  const float* __restrict__ pred_diag,
                                                  float* __restrict__ Wout)
{
    const int b    = blockIdx.x;
    const int lane = threadIdx.x;
    const int s0   = lane * 4;
    float wr4[4], bg4[4], A4[4], B4[4], ur[4], ui[4], pr[4], pi[4];
#pragma unroll
    for (int i = 0; i < 4; ++i) {
        wr4[i] = consts[0 * MEMS + s0 + i];
        bg4[i] = consts[1 * MEMS + s0 + i];
        A4[i]  = consts[2 * MEMS + s0 + i];
        B4[i]  = consts[3 * MEMS + s0 + i];
        ur[i]  = consts[4 * MEMS + s0 + i];
        ui[i]  = consts[5 * MEMS + s0 + i];
        pr[i] = ur[i]; pi[i] = ui[i];
    }
    const int general = flags[0] | flags[1];
    const size_t base = (size_t)b * TT * MEMS + s0;

    if (!general) {
        // ------------------------ FAST PATH ------------------------
        float4 mbuf[8];
        float  kb[8];
#pragma unroll
        for (int j = 0; j < 8; ++j) {
            mbuf[j] = *(const float4*)&M[base + (size_t)j * MEMS];
            kb[j]   = kth[b * TT + j];
        }
        float invc = 1.0f, invp = 1.0f;
        for (int t0 = 0; t0 < TT; t0 += 8) {
#pragma unroll
            for (int j = 0; j < 8; ++j) {
                const int t = t0 + j;
                const float4 mcur = mbuf[j];
                const float  kcur = kb[j];
                if (t + 8 < TT) {
                    mbuf[j] = *(const float4*)&M[base + (size_t)(t + 8) * MEMS];
                    kb[j]   = kth[b * TT + t + 8];
                }
                const float mv[4] = {mcur.x, mcur.y, mcur.z, mcur.w};
                float u1r[4], u1i[4];
                float ss = 0.0f;
#pragma unroll
                for (int i = 0; i < 4; ++i) {
                    const float binj = (fabsf(mv[i]) >= kcur) ? BETA * mv[i] : 0.0f;
                    const float Lr = A4[i] * ur[i] - B4[i] * ui[i];
                    const float Li = B4[i] * ur[i] + A4[i] * ui[i];
                    const float wi = wr4[i] * invp;
                    u1r[i] = fmaf(invc, Lr, fmaf(wi, pr[i], binj));
                    u1i[i] = fmaf(invc, Li, wi * pi[i]);
                    ss = fmaf(u1r[i], u1r[i], fmaf(u1i[i], u1i[i], ss));
                }
                ss = wave_sum_bcast(ss);
                const float invn = __builtin_amdgcn_rsqf(fmaxf(ss, 1e-16f));
                float wv[4];
#pragma unroll
                for (int i = 0; i < 4; ++i) {
                    wv[i] = bg4[i] * (u1r[i] * invn);
                    pr[i] = ur[i]; pi[i] = ui[i];
                    ur[i] = u1r[i]; ui[i] = u1i[i];
                }
                invp = invc; invc = invn;
                float4 wq = {wv[0], wv[1], wv[2], wv[3]};
                *(float4*)&Wout[base + (size_t)t * MEMS] = wq;
            }
        }
        return;
    }

    // ------------------------ GENERAL PATH ------------------------
    float rc4[4], rs4[4], ed4[4], pd4[4];
#pragma unroll
    for (int i = 0; i < 4; ++i) {
        rc4[i] = consts[6 * MEMS + s0 + i];
        rs4[i] = consts[7 * MEMS + s0 + i];
        ed4[i] = eps_diag[s0 + i];
        pd4[i] = pred_diag[s0 + i];
    }
    const float eta  = consts[8 * MEMS];
    const int es_any = flags[0];
    const int ps_any = flags[1];
    // state here is normalized each step: ur/ui = z, pr/pi = prev
    float4 mbuf[4];
    float  kb4[4];
#pragma unroll
    for (int j = 0; j < 4; ++j) {
        mbuf[j] = *(const float4*)&M[base + (size_t)j * MEMS];
        kb4[j]  = kth[b * TT + j];
    }
    for (int t0 = 0; t0 < TT; t0 += 4) {
#pragma unroll
        for (int j = 0; j < 4; ++j) {
            const int t = t0 + j;
            const float4 mcur = mbuf[j];
            const float  kcur = kb4[j];
            if (t + 4 < TT) {
                mbuf[j] = *(const float4*)&M[base + (size_t)(t + 4) * MEMS];
                kb4[j]  = kth[b * TT + t + 4];
            }
            float rr[4], ri[4], nr[4], ni[4];
#pragma unroll
            for (int i = 0; i < 4; ++i) {
                rr[i] = ur[i] * rc4[i] - ui[i] * rs4[i];
                ri[i] = ur[i] * rs4[i] + ui[i] * rc4[i];
            }
            const float mv[4] = {mcur.x, mcur.y, mcur.z, mcur.w};
#pragma unroll
            for (int i = 0; i < 4; ++i) {
                const float inj = (fabsf(mv[i]) >= kcur) ? mv[i] : 0.0f;
                nr[i] = GAMMA * rr[i] + wr4[i] * pr[i] + eta * ed4[i] * rr[i]
                        - PTS * pd4[i] * ri[i] + BETA * inj;
                ni[i] = GAMMA * ri[i] + wr4[i] * pi[i] + eta * ed4[i] * ri[i]
                        + PTS * pd4[i] * rr[i];
            }
            if (es_any) {
#pragma unroll
                for (int k = 0; k < RANKC; ++k) {
                    float u[4], prj = 0.0f, pij = 0.0f;
#pragma unroll
                    for (int i = 0; i < 4; ++i) {
                        u[i] = eps_fac[(size_t)(s0 + i) * RANKC + k];
                        prj = fmaf(u[i], rr[i], prj);
                        pij = fmaf(u[i], ri[i], pij);
                    }
                    prj = wave_sum_bcast(prj);
                    pij = wave_sum_bcast(pij);
                    const float sc = eta * eps_scale[k];
#pragma unroll
                    for (int i = 0; i < 4; ++i) {
                        nr[i] = fmaf(sc * u[i], prj, nr[i]);
                        ni[i] = fmaf(sc * u[i], pij, ni[i]);
                    }
                }
            }
            if (ps_any) {
#pragma unroll
                for (int k = 0; k < RANKC; ++k) {
                    float u[4], qrj = 0.0f, qij = 0.0f;
#pragma unroll
                    for (int i = 0; i < 4; ++i) {
                        u[i] = pred_fac[(size_t)(s0 + i) * RANKC + k];
                        qrj = fmaf(u[i], rr[i], qrj);
                        qij = fmaf(u[i], ri[i], qij);
                    }
                    qrj = wave_sum_bcast(qrj);
                    qij = wave_sum_bcast(qij);
                    const float sc = PTS * pred_scale[k];
#pragma unroll
                    for (int i = 0; i < 4; ++i) {
                        nr[i] = fmaf(-sc * u[i], qij, nr[i]);  // re -= sc*pred_im
                        ni[i] = fmaf( sc * u[i], qrj, ni[i]);  // im += sc*pred_re
                    }
                }
            }
            float ss = 0.0f;
#pragma unroll
            for (int i = 0; i < 4; ++i) ss = fmaf(nr[i], nr[i], fmaf(ni[i], ni[i], ss));
            ss = wave_sum_bcast(ss);
            const float inv = __builtin_amdgcn_rsqf(fmaxf(ss, 1e-16f));
            float wv[4];
#pragma unroll
            for (int i = 0; i < 4; ++i) {
                const float znr = nr[i] * inv, zni = ni[i] * inv;
                pr[i] = ur[i]; pi[i] = ui[i];
                ur[i] = znr;   ui[i] = zni;
                wv[i] = bg4[i] * znr;
            }
            float4 wq = {wv[0], wv[1], wv[2], wv[3]};
            *(float4*)&Wout[base + (size_t)t * MEMS] = wq;
        }
    }
}

// ---------------------------------------------------------------------------
// outp: Y(R x 1024) = X + alpha * W(R x 256) * basisT
// ---------------------------------------------------------------------------
__global__ __launch_bounds__(256) void outp_kernel(const float* __restrict__ W,
                                                   const float* __restrict__ basis,
                                                   const float* __restrict__ x,
                                                   const float* __restrict__ alpha_p,
                                                   float* __restrict__ y)
{
    __shared__ float As[32][68];  // [k][m]
    __shared__ float Bs[32][68];  // [k][n]
    const int tid  = threadIdx.x;
    const int row0 = blockIdx.x * 64;
    const int col0 = blockIdx.y * 64;  // h
    const int mt = tid >> 4, nt = tid & 15;
    float acc[4][4] = {};
    for (int k0 = 0; k0 < MEMS; k0 += 32) {
        {
            int q = tid, m = q >> 3, kq = q & 7;
            float4 a = *(const float4*)&W[(size_t)(row0 + m) * MEMS + k0 + kq * 4];
            As[kq * 4 + 0][m] = a.x; As[kq * 4 + 1][m] = a.y;
            As[kq * 4 + 2][m] = a.z; As[kq * 4 + 3][m] = a.w;
            q = tid + 256; m = q >> 3; kq = q & 7;
            float4 b = *(const float4*)&W[(size_t)(row0 + m) * MEMS + k0 + kq * 4];
            As[kq * 4 + 0][m] = b.x; As[kq * 4 + 1][m] = b.y;
            As[kq * 4 + 2][m] = b.z; As[kq * 4 + 3][m] = b.w;
            q = tid; int n = q >> 3; kq = q & 7;
            float4 c = *(const float4*)&basis[(size_t)(col0 + n) * SLOTS + k0 + kq * 4];
            Bs[kq * 4 + 0][n] = c.x; Bs[kq * 4 + 1][n] = c.y;
            Bs[kq * 4 + 2][n] = c.z; Bs[kq * 4 + 3][n] = c.w;
            q = tid + 256; n = q >> 3; kq = q & 7;
            float4 d = *(const float4*)&basis[(size_t)(col0 + n) * SLOTS + k0 + kq * 4];
            Bs[kq * 4 + 0][n] = d.x; Bs[kq * 4 + 1][n] = d.y;
            Bs[kq * 4 + 2][n] = d.z; Bs[kq * 4 + 3][n] = d.w;
        }
        __syncthreads();
#pragma unroll
        for (int kk = 0; kk < 32; ++kk) {
            float4 a = *(const float4*)&As[kk][mt * 4];
            float4 b = *(const float4*)&Bs[kk][nt * 4];
            float av[4] = {a.x, a.y, a.z, a.w};
            float bv[4] = {b.x, b.y, b.z, b.w};
#pragma unroll
            for (int i = 0; i < 4; ++i)
#pragma unroll
                for (int j = 0; j < 4; ++j) acc[i][j] += av[i] * bv[j];
        }
        __syncthreads();
    }
    const float alpha = alpha_p[0];
#pragma unroll
    for (int i = 0; i < 4; ++i) {
        const size_t ro = (size_t)(row0 + mt * 4 + i) * HD + col0 + nt * 4;
        float4 xv = *(const float4*)&x[ro];
        float4 o  = {xv.x + alpha * acc[i][0], xv.y + alpha * acc[i][1],
                     xv.z + alpha * acc[i][2], xv.w + alpha * acc[i][3]};
        *(float4*)&y[ro] = o;
    }
}

// ---------------------------------------------------------------------------
extern "C" void kernel_launch(void* const* d_in, const int* in_sizes, int n_in,
                              void* d_out, int out_size, void* d_ws, size_t ws_size,
                              hipStream_t stream)
{
    const float* x          = (const float*)d_in[0];
    const float* basis      = (const float*)d_in[1];
    const float* t0re       = (const float*)d_in[2];
    const float* t0im       = (const float*)d_in[3];
    const float* eta_raw    = (const float*)d_in[4];
    const float* alpha      = (const float*)d_in[5];
    const float* trot       = (const float*)d_in[6];
    const float* w_r        = (const float*)d_in[7];
    const float* bgate      = (const float*)d_in[8];
    const float* eps_fac    = (const float*)d_in[9];
    const float* eps_scale  = (const float*)d_in[10];
    const float* eps_diag   = (const float*)d_in[11];
    const float* pred_fac   = (const float*)d_in[12];
    const float* pred_scale = (const float*)d_in[13];
    const float* pred_diag  = (const float*)d_in[14];
    float* out = (float*)d_out;

    const size_t szM = (size_t)RR * MEMS * sizeof(float);  // 32 MB
    const size_t szW = szM;                                 // 32 MB
    const size_t szK = (size_t)RR * sizeof(float);          // 128 KB
    const size_t szC = 16384;                               // consts + flags

    char* ws = (char*)d_ws;
    float *Mbuf, *Wbuf, *kbuf, *cbuf;
    if (ws_size >= szM + szW + szK + szC) {
        Mbuf = (float*)(ws);
        Wbuf = (float*)(ws + szM);
        kbuf = (float*)(ws + szM + szW);
        cbuf = (float*)(ws + szM + szW + szK);
    } else {
        // fallback: stage M in d_out (consumed by topk+scan before outp rewrites it)
        Mbuf = (float*)d_out;
        Wbuf = (float*)(ws);
        kbuf = (float*)(ws + szW);
        cbuf = (float*)(ws + szW + szK);
    }
    int* fbuf = (int*)(cbuf + 8 * MEMS + 16);

    prep_kernel<<<1, 256, 0, stream>>>(t0re, t0im, eta_raw, trot, w_r, bgate,
                                       eps_scale, pred_scale, eps_diag, pred_diag,
                                       cbuf, fbuf);
    proj_kernel<<<dim3(RR / 64, MEMS / 64), 256, 0, stream>>>(x, basis, Mbuf);
    topk_kernel<<<RR, 64, 0, stream>>>(Mbuf, kbuf);
    scan_kernel<<<BATCH, 64, 0, stream>>>(Mbuf, kbuf, cbuf, fbuf,
                                          eps_fac, eps_scale, eps_diag,
                                          pred_fac, pred_scale, pred_diag, Wbuf);
    outp_kernel<<<dim3(RR / 64, HD / 64), 256, 0, stream>>>(Wbuf, basis, x, alpha, out);
}

// Round 3
// 1306.447 us; speedup vs baseline: 2.0696x; 1.1681x over previous
//
#include <hip/hip_runtime.h>
#include <cstdint>
#include <cstddef>

#define HD    1024
#define SLOTS 272
#define MEMS  256
#define BATCH 8
#define TT    4096
#define RR    (BATCH*TT)
#define RANKC 10

#define GAMMA 0.92f
#define BETA  0.08f
#define PTS   0.4f

// ---------------------------------------------------------------------------
// DPP wave64 sum-allreduce: 6 VALU-speed cross-lane adds + readlane broadcast.
// ---------------------------------------------------------------------------
#define DPP_ADD(v, ctrl, rmask)                                                   \
    v += __int_as_float(__builtin_amdgcn_update_dpp(                              \
        0, __float_as_int(v), (ctrl), (rmask), 0xf, true))

__device__ __forceinline__ float wave_sum_bcast(float v)
{
    DPP_ADD(v, 0xB1,  0xf);   // quad_perm [1,0,3,2]  : + lane^1
    DPP_ADD(v, 0x4E,  0xf);   // quad_perm [2,3,0,1]  : + lane^2
    DPP_ADD(v, 0x141, 0xf);   // row_half_mirror      : + other quad
    DPP_ADD(v, 0x140, 0xf);   // row_mirror           : + other 8-group
    DPP_ADD(v, 0x142, 0xa);   // row_bcast15 -> rows 1,3
    DPP_ADD(v, 0x143, 0xc);   // row_bcast31 -> rows 2,3 (lane 63 = total)
    return __int_as_float(__builtin_amdgcn_readlane(__float_as_int(v), 63));
}

// ---------------------------------------------------------------------------
// prep: per-slot constants.
// consts (floats): [0]=wr[256] [256]=bg[256] [512]=A[256] [768]=B[256]
// [1024]=z0re[256] [1280]=z0im[256] [1536]=cos[256] [1792]=sin[256] [2048]=eta
//   c1 = gamma + eta*eps_diag, c2 = PTS*pred_diag, A = c1*cos - c2*sin,
//   B = c1*sin + c2*cos.  flags: [0]=eps_scale any nz, [1]=pred_scale any nz.
// ---------------------------------------------------------------------------
__global__ void prep_kernel(const float* __restrict__ t0re, const float* __restrict__ t0im,
                            const float* __restrict__ eta_raw,
                            const float* __restrict__ trot, const float* __restrict__ w_r,
                            const float* __restrict__ bgate,
                            const float* __restrict__ eps_scale, const float* __restrict__ pred_scale,
                            const float* __restrict__ eps_diag, const float* __restrict__ pred_diag,
                            float* __restrict__ consts, int* __restrict__ flags)
{
    __shared__ float red[MEMS];
    const int s = threadIdx.x;  // 256 threads
    const float tr = t0re[s], ti = t0im[s];
    red[s] = tr * tr + ti * ti;
    __syncthreads();
    for (int off = 128; off > 0; off >>= 1) {
        if (s < off) red[s] += red[s + off];
        __syncthreads();
    }
    const float nrm = sqrtf(fmaxf(red[0], 1e-16f));
    const float eta = log1pf(expf(eta_raw[0]));
    const float rc = cosf(trot[s]), rs = sinf(trot[s]);
    const float c1 = GAMMA + eta * eps_diag[s];
    const float c2 = PTS * pred_diag[s];
    consts[0 * MEMS + s] = 1.0f / (1.0f + expf(-w_r[s]));
    consts[1 * MEMS + s] = 1.0f / (1.0f + expf(-bgate[s]));
    consts[2 * MEMS + s] = c1 * rc - c2 * rs;   // A
    consts[3 * MEMS + s] = c1 * rs + c2 * rc;   // B
    consts[4 * MEMS + s] = tr / nrm;
    consts[5 * MEMS + s] = ti / nrm;
    consts[6 * MEMS + s] = rc;
    consts[7 * MEMS + s] = rs;
    if (s == 0) {
        consts[8 * MEMS] = eta;
        int f1 = 0, f2 = 0;
        for (int k = 0; k < RANKC; ++k) {
            if (eps_scale[k]  != 0.0f) f1 = 1;
            if (pred_scale[k] != 0.0f) f2 = 1;
        }
        flags[0] = f1;
        flags[1] = f2;
    }
}

// ---------------------------------------------------------------------------
// proj: M(R x 256) = X(R x 1024) * Q,  Q[k][n] = basis[k*272 + n]
// ---------------------------------------------------------------------------
__global__ __launch_bounds__(256) void proj_kernel(const float* __restrict__ x,
                                                   const float* __restrict__ basis,
                                                   float* __restrict__ M)
{
    __shared__ float As[32][68];  // [k][m], padded
    __shared__ float Bs[32][68];  // [k][n], padded
    const int tid  = threadIdx.x;
    const int row0 = blockIdx.x * 64;
    const int col0 = blockIdx.y * 64;
    const int mt = tid >> 4, nt = tid & 15;
    float acc[4][4] = {};
    for (int k0 = 0; k0 < HD; k0 += 32) {
        {
            int q = tid, m = q >> 3, kq = q & 7;
            float4 a = *(const float4*)&x[(size_t)(row0 + m) * HD + k0 + kq * 4];
            As[kq * 4 + 0][m] = a.x; As[kq * 4 + 1][m] = a.y;
            As[kq * 4 + 2][m] = a.z; As[kq * 4 + 3][m] = a.w;
            q = tid + 256; m = q >> 3; kq = q & 7;
            float4 b = *(const float4*)&x[(size_t)(row0 + m) * HD + k0 + kq * 4];
            As[kq * 4 + 0][m] = b.x; As[kq * 4 + 1][m] = b.y;
            As[kq * 4 + 2][m] = b.z; As[kq * 4 + 3][m] = b.w;
            q = tid; int k = q >> 4; int nq = q & 15;
            float4 c = *(const float4*)&basis[(size_t)(k0 + k) * SLOTS + col0 + nq * 4];
            *(float4*)&Bs[k][nq * 4] = c;
            q = tid + 256; k = q >> 4; nq = q & 15;
            float4 d = *(const float4*)&basis[(size_t)(k0 + k) * SLOTS + col0 + nq * 4];
            *(float4*)&Bs[k][nq * 4] = d;
        }
        __syncthreads();
#pragma unroll
        for (int kk = 0; kk < 32; ++kk) {
            float4 a = *(const float4*)&As[kk][mt * 4];
            float4 b = *(const float4*)&Bs[kk][nt * 4];
            float av[4] = {a.x, a.y, a.z, a.w};
            float bv[4] = {b.x, b.y, b.z, b.w};
#pragma unroll
            for (int i = 0; i < 4; ++i)
#pragma unroll
                for (int j = 0; j < 4; ++j) acc[i][j] += av[i] * bv[j];
        }
        __syncthreads();
    }
#pragma unroll
    for (int i = 0; i < 4; ++i) {
        float4 o = {acc[i][0], acc[i][1], acc[i][2], acc[i][3]};
        *(float4*)&M[(size_t)(row0 + mt * 4 + i) * MEMS + col0 + nt * 4] = o;
    }
}

// ---------------------------------------------------------------------------
// topk: per (b,t) row, find 8th-largest |m| (dup-counting), then mask the row
// IN PLACE: M[r,s] <- (|m|>=kth) ? BETA*m : 0.  Scan consumes it directly.
// ---------------------------------------------------------------------------
__global__ __launch_bounds__(64) void topk_kernel(float* __restrict__ M)
{
    const int r    = blockIdx.x;
    const int lane = threadIdx.x;
    float4 v = *(const float4*)&M[(size_t)r * MEMS + lane * 4];
    float vals[4] = {fabsf(v.x), fabsf(v.y), fabsf(v.z), fabsf(v.w)};
    float keep[4] = {vals[0], vals[1], vals[2], vals[3]};
    float kv = 0.0f;
#pragma unroll
    for (int it = 0; it < 8; ++it) {
        float lm = vals[0]; int li = 0;
#pragma unroll
        for (int j = 1; j < 4; ++j)
            if (vals[j] > lm) { lm = vals[j]; li = j; }
        float bm = lm; int bi = lane * 4 + li;
#pragma unroll
        for (int off = 1; off < 64; off <<= 1) {
            float om = __shfl_xor(bm, off);
            int   oi = __shfl_xor(bi, off);
            if (om > bm || (om == bm && oi < bi)) { bm = om; bi = oi; }
        }
        kv = bm;
        if ((bi >> 2) == lane) vals[bi & 3] = -1.0f;
    }
    float4 o;
    o.x = (keep[0] >= kv) ? BETA * v.x : 0.0f;
    o.y = (keep[1] >= kv) ? BETA * v.y : 0.0f;
    o.z = (keep[2] >= kv) ? BETA * v.z : 0.0f;
    o.w = (keep[3] >= kv) ? BETA * v.w : 0.0f;
    *(float4*)&M[(size_t)r * MEMS + lane * 4] = o;
}

// ---------------------------------------------------------------------------
// scan: one wave per batch, 4 slots/lane, all state in registers.
// M is pre-masked (= BETA*inj).  Deferred normalization: carry unnormalized u
// plus uniform invc=1/||u_t||, invp=1/||u_{t-1}||.  Stores RAW u1 (float4) and
// one inv scalar per step; outp applies inv*alpha (per row) and bg (per col).
// Depth-16 prefetch ring; prefetch may read <=16 rows past the slice (valid
// adjacent ws/d_out memory, values unused).
// ---------------------------------------------------------------------------
__global__ __launch_bounds__(64) void scan_kernel(const float* __restrict__ M,
                                                  const float* __restrict__ consts,
                                                  const int* __restrict__ flags,
                                                  const float* __restrict__ eps_fac,
                                                  const float* __restrict__ eps_scale,
                                                  const float* __restrict__ eps_diag,
                                                  const float* __restrict__ pred_fac,
                                                  const float* __restrict__ pred_scale,
                                                  const float* __restrict__ pred_diag,
                                                  float* __restrict__ Wout,
                                                  float* __restrict__ invb)
{
    const int b    = blockIdx.x;
    const int lane = threadIdx.x;
    const int s0   = lane * 4;
    float wr4[4], A4[4], B4[4], ur[4], ui[4], pr[4], pi[4];
#pragma unroll
    for (int i = 0; i < 4; ++i) {
        wr4[i] = consts[0 * MEMS + s0 + i];
        A4[i]  = consts[2 * MEMS + s0 + i];
        B4[i]  = consts[3 * MEMS + s0 + i];
        ur[i]  = consts[4 * MEMS + s0 + i];
        ui[i]  = consts[5 * MEMS + s0 + i];
        pr[i] = ur[i]; pi[i] = ui[i];
    }
    const int general = flags[0] | flags[1];
    const size_t base = (size_t)b * TT * MEMS + s0;
    float* ib = invb + b * TT;

    if (!general) {
        // ------------------------ FAST PATH ------------------------
        float4 mbuf[16];
#pragma unroll
        for (int j = 0; j < 16; ++j)
            mbuf[j] = *(const float4*)&M[base + (size_t)j * MEMS];
        float invc = 1.0f, invp = 1.0f;
        for (int t0 = 0; t0 < TT; t0 += 16) {
#pragma unroll
            for (int j = 0; j < 16; ++j) {
                const int t = t0 + j;
                const float4 mc = mbuf[j];
                mbuf[j] = *(const float4*)&M[base + (size_t)(t + 16) * MEMS];
                const float mv[4] = {mc.x, mc.y, mc.z, mc.w};
                float u1r[4], u1i[4];
#pragma unroll
                for (int i = 0; i < 4; ++i) {
                    const float Lr  = fmaf(A4[i], ur[i], -B4[i] * ui[i]);
                    const float Li  = fmaf(B4[i], ur[i],  A4[i] * ui[i]);
                    const float wpr = wr4[i] * pr[i];
                    const float wpi = wr4[i] * pi[i];
                    u1r[i] = fmaf(invc, Lr, fmaf(invp, wpr, mv[i]));
                    u1i[i] = fmaf(invc, Li, invp * wpi);
                }
                const float p0 = fmaf(u1i[0], u1i[0], u1r[0] * u1r[0]);
                const float p1 = fmaf(u1i[1], u1i[1], u1r[1] * u1r[1]);
                const float p2 = fmaf(u1i[2], u1i[2], u1r[2] * u1r[2]);
                const float p3 = fmaf(u1i[3], u1i[3], u1r[3] * u1r[3]);
                float ss = (p0 + p1) + (p2 + p3);
                ss = wave_sum_bcast(ss);
                const float invn = __builtin_amdgcn_rsqf(fmaxf(ss, 1e-16f));
                float4 wq = {u1r[0], u1r[1], u1r[2], u1r[3]};
                *(float4*)&Wout[base + (size_t)t * MEMS] = wq;
                if (lane == 0) ib[t] = invn;
#pragma unroll
                for (int i = 0; i < 4; ++i) {
                    pr[i] = ur[i]; pi[i] = ui[i];
                    ur[i] = u1r[i]; ui[i] = u1i[i];
                }
                invp = invc; invc = invn;
            }
        }
        return;
    }

    // ------------------------ GENERAL PATH ------------------------
    float rc4[4], rs4[4], ed4[4], pd4[4];
#pragma unroll
    for (int i = 0; i < 4; ++i) {
        rc4[i] = consts[6 * MEMS + s0 + i];
        rs4[i] = consts[7 * MEMS + s0 + i];
        ed4[i] = eps_diag[s0 + i];
        pd4[i] = pred_diag[s0 + i];
    }
    const float eta  = consts[8 * MEMS];
    const int es_any = flags[0];
    const int ps_any = flags[1];
    float4 mbuf[4];
#pragma unroll
    for (int j = 0; j < 4; ++j)
        mbuf[j] = *(const float4*)&M[base + (size_t)j * MEMS];
    for (int t0 = 0; t0 < TT; t0 += 4) {
#pragma unroll
        for (int j = 0; j < 4; ++j) {
            const int t = t0 + j;
            const float4 mc = mbuf[j];
            mbuf[j] = *(const float4*)&M[base + (size_t)(t + 4) * MEMS];
            float rr[4], ri[4], nr[4], ni[4];
#pragma unroll
            for (int i = 0; i < 4; ++i) {
                rr[i] = ur[i] * rc4[i] - ui[i] * rs4[i];
                ri[i] = ur[i] * rs4[i] + ui[i] * rc4[i];
            }
            const float mv[4] = {mc.x, mc.y, mc.z, mc.w};
#pragma unroll
            for (int i = 0; i < 4; ++i) {
                nr[i] = GAMMA * rr[i] + wr4[i] * pr[i] + eta * ed4[i] * rr[i]
                        - PTS * pd4[i] * ri[i] + mv[i];   // mv already BETA*inj
                ni[i] = GAMMA * ri[i] + wr4[i] * pi[i] + eta * ed4[i] * ri[i]
                        + PTS * pd4[i] * rr[i];
            }
            if (es_any) {
#pragma unroll
                for (int k = 0; k < RANKC; ++k) {
                    float u[4], prj = 0.0f, pij = 0.0f;
#pragma unroll
                    for (int i = 0; i < 4; ++i) {
                        u[i] = eps_fac[(size_t)(s0 + i) * RANKC + k];
                        prj = fmaf(u[i], rr[i], prj);
                        pij = fmaf(u[i], ri[i], pij);
                    }
                    prj = wave_sum_bcast(prj);
                    pij = wave_sum_bcast(pij);
                    const float sc = eta * eps_scale[k];
#pragma unroll
                    for (int i = 0; i < 4; ++i) {
                        nr[i] = fmaf(sc * u[i], prj, nr[i]);
                        ni[i] = fmaf(sc * u[i], pij, ni[i]);
                    }
                }
            }
            if (ps_any) {
#pragma unroll
                for (int k = 0; k < RANKC; ++k) {
                    float u[4], qrj = 0.0f, qij = 0.0f;
#pragma unroll
                    for (int i = 0; i < 4; ++i) {
                        u[i] = pred_fac[(size_t)(s0 + i) * RANKC + k];
                        qrj = fmaf(u[i], rr[i], qrj);
                        qij = fmaf(u[i], ri[i], qij);
                    }
                    qrj = wave_sum_bcast(qrj);
                    qij = wave_sum_bcast(qij);
                    const float sc = PTS * pred_scale[k];
#pragma unroll
                    for (int i = 0; i < 4; ++i) {
                        nr[i] = fmaf(-sc * u[i], qij, nr[i]);
                        ni[i] = fmaf( sc * u[i], qrj, ni[i]);
                    }
                }
            }
            float ss = 0.0f;
#pragma unroll
            for (int i = 0; i < 4; ++i) ss = fmaf(nr[i], nr[i], fmaf(ni[i], ni[i], ss));
            ss = wave_sum_bcast(ss);
            const float inv = __builtin_amdgcn_rsqf(fmaxf(ss, 1e-16f));
            float4 wq = {nr[0], nr[1], nr[2], nr[3]};
            *(float4*)&Wout[base + (size_t)t * MEMS] = wq;
            if (lane == 0) ib[t] = inv;
#pragma unroll
            for (int i = 0; i < 4; ++i) {
                pr[i] = ur[i]; pi[i] = ui[i];
                ur[i] = nr[i] * inv; ui[i] = ni[i] * inv;
            }
        }
    }
}

// ---------------------------------------------------------------------------
// outp: Y = X + alpha * (inv[row] * W) * (bg[k] * basisT).  alpha*inv folded
// into the A-tile load; bg folded into the B-tile load.
// ---------------------------------------------------------------------------
__global__ __launch_bounds__(256) void outp_kernel(const float* __restrict__ W,
                                                   const float* __restrict__ basis,
                                                   const float* __restrict__ x,
                                                   const float* __restrict__ alpha_p,
                                                   const float* __restrict__ consts,
                                                   const float* __restrict__ invb,
                                                   float* __restrict__ y)
{
    __shared__ float As[32][68];  // [k][m]
    __shared__ float Bs[32][68];  // [k][n]
    const int tid  = threadIdx.x;
    const int row0 = blockIdx.x * 64;
    const int col0 = blockIdx.y * 64;  // h
    const int mt = tid >> 4, nt = tid & 15;
    const float alpha = alpha_p[0];
    const float* bgc  = consts + MEMS;
    const int m0 = tid >> 3, m1 = (tid + 256) >> 3;
    const float sA0 = alpha * invb[row0 + m0];
    const float sA1 = alpha * invb[row0 + m1];
    const int kq0 = tid & 7;
    float acc[4][4] = {};
    for (int k0 = 0; k0 < MEMS; k0 += 32) {
        {
            const float4 bgv = *(const float4*)&bgc[k0 + kq0 * 4];
            float4 a = *(const float4*)&W[(size_t)(row0 + m0) * MEMS + k0 + kq0 * 4];
            As[kq0 * 4 + 0][m0] = a.x * sA0; As[kq0 * 4 + 1][m0] = a.y * sA0;
            As[kq0 * 4 + 2][m0] = a.z * sA0; As[kq0 * 4 + 3][m0] = a.w * sA0;
            float4 b = *(const float4*)&W[(size_t)(row0 + m1) * MEMS + k0 + kq0 * 4];
            As[kq0 * 4 + 0][m1] = b.x * sA1; As[kq0 * 4 + 1][m1] = b.y * sA1;
            As[kq0 * 4 + 2][m1] = b.z * sA1; As[kq0 * 4 + 3][m1] = b.w * sA1;
            int q = tid; int n = q >> 3;
            float4 c = *(const float4*)&basis[(size_t)(col0 + n) * SLOTS + k0 + kq0 * 4];
            Bs[kq0 * 4 + 0][n] = c.x * bgv.x; Bs[kq0 * 4 + 1][n] = c.y * bgv.y;
            Bs[kq0 * 4 + 2][n] = c.z * bgv.z; Bs[kq0 * 4 + 3][n] = c.w * bgv.w;
            q = tid + 256; n = q >> 3;
            float4 d = *(const float4*)&basis[(size_t)(col0 + n) * SLOTS + k0 + kq0 * 4];
            Bs[kq0 * 4 + 0][n] = d.x * bgv.x; Bs[kq0 * 4 + 1][n] = d.y * bgv.y;
            Bs[kq0 * 4 + 2][n] = d.z * bgv.z; Bs[kq0 * 4 + 3][n] = d.w * bgv.w;
        }
        __syncthreads();
#pragma unroll
        for (int kk = 0; kk < 32; ++kk) {
            float4 a = *(const float4*)&As[kk][mt * 4];
            float4 b = *(const float4*)&Bs[kk][nt * 4];
            float av[4] = {a.x, a.y, a.z, a.w};
            float bv[4] = {b.x, b.y, b.z, b.w};
#pragma unroll
            for (int i = 0; i < 4; ++i)
#pragma unroll
                for (int j = 0; j < 4; ++j) acc[i][j] += av[i] * bv[j];
        }
        __syncthreads();
    }
#pragma unroll
    for (int i = 0; i < 4; ++i) {
        const size_t ro = (size_t)(row0 + mt * 4 + i) * HD + col0 + nt * 4;
        float4 xv = *(const float4*)&x[ro];
        float4 o  = {xv.x + acc[i][0], xv.y + acc[i][1],
                     xv.z + acc[i][2], xv.w + acc[i][3]};
        *(float4*)&y[ro] = o;
    }
}

// ---------------------------------------------------------------------------
extern "C" void kernel_launch(void* const* d_in, const int* in_sizes, int n_in,
                              void* d_out, int out_size, void* d_ws, size_t ws_size,
                              hipStream_t stream)
{
    const float* x          = (const float*)d_in[0];
    const float* basis      = (const float*)d_in[1];
    const float* t0re       = (const float*)d_in[2];
    const float* t0im       = (const float*)d_in[3];
    const float* eta_raw    = (const float*)d_in[4];
    const float* alpha      = (const float*)d_in[5];
    const float* trot       = (const float*)d_in[6];
    const float* w_r        = (const float*)d_in[7];
    const float* bgate      = (const float*)d_in[8];
    const float* eps_fac    = (const float*)d_in[9];
    const float* eps_scale  = (const float*)d_in[10];
    const float* eps_diag   = (const float*)d_in[11];
    const float* pred_fac   = (const float*)d_in[12];
    const float* pred_scale = (const float*)d_in[13];
    const float* pred_diag  = (const float*)d_in[14];
    float* out = (float*)d_out;

    const size_t szM = (size_t)RR * MEMS * sizeof(float);  // 32 MB
    const size_t szW = szM;                                 // 32 MB
    const size_t szI = (size_t)RR * sizeof(float);          // 128 KB
    const size_t szC = 16384;                               // consts + flags

    char* ws = (char*)d_ws;
    float *Mbuf, *Wbuf, *ibuf, *cbuf;
    if (ws_size >= szM + szW + szI + szC) {
        Mbuf = (float*)(ws);
        Wbuf = (float*)(ws + szM);
        ibuf = (float*)(ws + szM + szW);
        cbuf = (float*)(ws + szM + szW + szI);
    } else {
        // fallback: stage M in d_out (consumed by topk+scan before outp rewrites it)
        Mbuf = (float*)d_out;
        Wbuf = (float*)(ws);
        ibuf = (float*)(ws + szW);
        cbuf = (float*)(ws + szW + szI);
    }
    int* fbuf = (int*)(cbuf + 8 * MEMS + 16);

    prep_kernel<<<1, 256, 0, stream>>>(t0re, t0im, eta_raw, trot, w_r, bgate,
                                       eps_scale, pred_scale, eps_diag, pred_diag,
                                       cbuf, fbuf);
    proj_kernel<<<dim3(RR / 64, MEMS / 64), 256, 0, stream>>>(x, basis, Mbuf);
    topk_kernel<<<RR, 64, 0, stream>>>(Mbuf);
    scan_kernel<<<BATCH, 64, 0, stream>>>(Mbuf, cbuf, fbuf,
                                          eps_fac, eps_scale, eps_diag,
                                          pred_fac, pred_scale, pred_diag,
                                          Wbuf, ibuf);
    outp_kernel<<<dim3(RR / 64, HD / 64), 256, 0, stream>>>(Wbuf, basis, x, alpha,
                                                            cbuf, ibuf, out);
}